// Round 1
// baseline (311.295 us; speedup 1.0000x reference)
//
#include <hip/hip_runtime.h>

// Problem constants (MACE symmetric contraction)
#define B_NODES 4096
#define C_CH    256
#define I_DIM   16
#define K3      23
#define K2      4
#define K1      1

// Workspace layout (in floats):
//   U3w : C * 4096   (per-channel contracted corr-3 basis)
//   c2w : C * 256
//   c1w : C * 16
//   sT  : C * B      (intermediate s[b,c] stored TRANSPOSED (c-major) for coalescing)
static constexpr size_t OFF_U3W = 0;
static constexpr size_t OFF_C2W = OFF_U3W + (size_t)C_CH * 4096;
static constexpr size_t OFF_C1W = OFF_C2W + (size_t)C_CH * 256;
static constexpr size_t OFF_ST  = OFF_C1W + (size_t)C_CH * 16;

// ---------------------------------------------------------------------------
// Kernel 1: per-channel weight contraction of the fixed CG bases.
// grid = C blocks, 256 threads. Cost ~24M MAC total — negligible.
// ---------------------------------------------------------------------------
__global__ __launch_bounds__(256) void precompute_kernel(
    const float* __restrict__ U3, const float* __restrict__ U2,
    const float* __restrict__ U1, const float* __restrict__ w3,
    const float* __restrict__ w2, const float* __restrict__ w1,
    float* __restrict__ ws) {
  const int c = blockIdx.x;
  const int t = threadIdx.x;
  __shared__ float sw3[K3];
  __shared__ float sw2[K2];
  __shared__ float sw1;
  if (t < K3) sw3[t] = w3[c * K3 + t];
  if (t >= 32 && t < 32 + K2) sw2[t - 32] = w2[c * K2 + (t - 32)];
  if (t == 64) sw1 = w1[c];
  __syncthreads();

  // U3w[c][e] = sum_k U3[e][k] * w3[c][k],  e = (p*16+q)*16+i
  float* U3w = ws + OFF_U3W + (size_t)c * 4096;
  for (int e = t; e < 4096; e += 256) {
    const float* up = U3 + (size_t)e * K3;
    float acc = 0.f;
#pragma unroll
    for (int k = 0; k < K3; ++k) acc += up[k] * sw3[k];
    U3w[e] = acc;
  }
  // c2w[c][p*16+i] = sum_k U2[(p*16+i)*K2 + k] * w2[c][k]
  {
    const float* up = U2 + (size_t)t * K2;
    float acc = 0.f;
#pragma unroll
    for (int k = 0; k < K2; ++k) acc += up[k] * sw2[k];
    ws[OFF_C2W + (size_t)c * 256 + t] = acc;
  }
  // c1w[c][i] = U1[i] * w1[c]   (K1 == 1)
  if (t < I_DIM) ws[OFF_C1W + (size_t)c * 16 + t] = U1[t] * sw1;
}

// ---------------------------------------------------------------------------
// Kernel 2: main cubic contraction.
//   s[b,c] = sum_p x_p * ( c1_p + sum_q x_q * ( c2_pq + sum_i U3w_pqi * x_i ) )
// grid = (B/1024, C); block = 256 threads; each thread carries NB=4 nodes in
// registers so every 16B broadcast LDS read of U3w feeds 16 FMAs.
// ---------------------------------------------------------------------------
#define NB 4
__global__ __launch_bounds__(256) void contract_kernel(
    const float* __restrict__ x, float* __restrict__ ws) {
  const int c  = blockIdx.y;
  const int b0 = blockIdx.x * (256 * NB);
  const int t  = threadIdx.x;

  __shared__ float sU[4096];
  __shared__ float sc2[256];
  __shared__ float sc1[16];

  {
    const float4* src = (const float4*)(ws + OFF_U3W + (size_t)c * 4096);
    float4* dst = (float4*)sU;
    for (int e = t; e < 1024; e += 256) dst[e] = src[e];
  }
  sc2[t] = ws[OFF_C2W + (size_t)c * 256 + t];
  if (t < 16) sc1[t] = ws[OFF_C1W + (size_t)c * 16 + t];
  __syncthreads();

  // Load x for NB nodes (16 consecutive floats per node = one cache line).
  float xr[NB][16];
#pragma unroll
  for (int j = 0; j < NB; ++j) {
    const int b = b0 + j * 256 + t;
    const float4* xp = (const float4*)(x + ((size_t)b * C_CH + c) * I_DIM);
#pragma unroll
    for (int v = 0; v < 4; ++v) {
      float4 vv = xp[v];
      xr[j][v * 4 + 0] = vv.x;
      xr[j][v * 4 + 1] = vv.y;
      xr[j][v * 4 + 2] = vv.z;
      xr[j][v * 4 + 3] = vv.w;
    }
  }

  float acc[NB] = {0.f, 0.f, 0.f, 0.f};
  for (int p = 0; p < 16; ++p) {
    const float cp = sc1[p];
    float sp[NB];
#pragma unroll
    for (int j = 0; j < NB; ++j) sp[j] = cp;

#pragma unroll 4
    for (int q = 0; q < 16; ++q) {
      const float cq = sc2[p * 16 + q];
      float sq[NB];
#pragma unroll
      for (int j = 0; j < NB; ++j) sq[j] = cq;

      const float4* up = (const float4*)(sU + ((p * 16 + q) * 16));
#pragma unroll
      for (int v = 0; v < 4; ++v) {
        const float4 u = up[v];  // broadcast across all 64 lanes — conflict-free
#pragma unroll
        for (int j = 0; j < NB; ++j) {
          sq[j] += u.x * xr[j][v * 4 + 0];
          sq[j] += u.y * xr[j][v * 4 + 1];
          sq[j] += u.z * xr[j][v * 4 + 2];
          sq[j] += u.w * xr[j][v * 4 + 3];
        }
      }
#pragma unroll
      for (int j = 0; j < NB; ++j) sp[j] += sq[j] * xr[j][q];
    }
#pragma unroll
    for (int j = 0; j < NB; ++j) acc[j] += sp[j] * xr[j][p];
  }

  // Store transposed: sT[c][b] — consecutive threads write consecutive floats.
  float* sT = ws + OFF_ST + (size_t)c * B_NODES;
#pragma unroll
  for (int j = 0; j < NB; ++j) sT[b0 + j * 256 + t] = acc[j];
}

// ---------------------------------------------------------------------------
// Kernel 3: out[b,d] = (1/16) * sum_c sT[c,b] * W[c,d]
// Classic 64x64 tile fp32 GEMM, K=256. grid = (B/64, C/64) = (64,4).
// ---------------------------------------------------------------------------
__global__ __launch_bounds__(256) void linear_kernel(
    const float* __restrict__ ws, const float* __restrict__ W,
    float* __restrict__ out) {
  const float* sT = ws + OFF_ST;
  const int b0 = blockIdx.x * 64;
  const int d0 = blockIdx.y * 64;
  const int t  = threadIdx.x;
  const int tx = t & 15;   // d micro-tile
  const int ty = t >> 4;   // b micro-tile

  __shared__ float As[16][64];
  __shared__ float Bs[16][64];
  float acc[4][4] = {};

  for (int k0 = 0; k0 < C_CH; k0 += 16) {
    const int kk  = t >> 6;   // 0..3
    const int col = t & 63;
#pragma unroll
    for (int r = 0; r < 4; ++r) {
      As[kk + r * 4][col] = sT[(size_t)(k0 + kk + r * 4) * B_NODES + b0 + col];
      Bs[kk + r * 4][col] = W[(size_t)(k0 + kk + r * 4) * C_CH + d0 + col];
    }
    __syncthreads();
#pragma unroll
    for (int k = 0; k < 16; ++k) {
      float a[4], bv[4];
#pragma unroll
      for (int i = 0; i < 4; ++i) a[i] = As[k][ty * 4 + i];
#pragma unroll
      for (int j = 0; j < 4; ++j) bv[j] = Bs[k][tx * 4 + j];
#pragma unroll
      for (int i = 0; i < 4; ++i)
#pragma unroll
        for (int j = 0; j < 4; ++j) acc[i][j] += a[i] * bv[j];
    }
    __syncthreads();
  }

#pragma unroll
  for (int i = 0; i < 4; ++i) {
    float4 v = make_float4(acc[i][0] * 0.0625f, acc[i][1] * 0.0625f,
                           acc[i][2] * 0.0625f, acc[i][3] * 0.0625f);
    *(float4*)(out + (size_t)(b0 + ty * 4 + i) * C_CH + d0 + tx * 4) = v;
  }
}

extern "C" void kernel_launch(void* const* d_in, const int* in_sizes, int n_in,
                              void* d_out, int out_size, void* d_ws, size_t ws_size,
                              hipStream_t stream) {
  const float* x  = (const float*)d_in[0];
  const float* U3 = (const float*)d_in[1];
  const float* U2 = (const float*)d_in[2];
  const float* U1 = (const float*)d_in[3];
  const float* w3 = (const float*)d_in[4];
  const float* w2 = (const float*)d_in[5];
  const float* w1 = (const float*)d_in[6];
  const float* Wl = (const float*)d_in[7];
  float* ws  = (float*)d_ws;
  float* out = (float*)d_out;

  precompute_kernel<<<dim3(C_CH), dim3(256), 0, stream>>>(U3, U2, U1, w3, w2, w1, ws);
  contract_kernel<<<dim3(B_NODES / (256 * NB), C_CH), dim3(256), 0, stream>>>(x, ws);
  linear_kernel<<<dim3(B_NODES / 64, C_CH / 64), dim3(256), 0, stream>>>(ws, Wl, out);
}

// Round 2
// 218.878 us; speedup vs baseline: 1.4222x; 1.4222x over previous
//
#include <hip/hip_runtime.h>

// MACE symmetric contraction, B=4096 nodes, C=256 channels, I=16.
//
// Reformulation: per (b,c),
//   s[b,c] = sum_p x_p * t[b,p],
//   t[b,p] = sum_{k<256} U3w[c,p,q,i]*x_q*x_i  (k=q*16+i)
//          + sum_{q}     c2[c,p,q]*x_q          (k=256+q)
//          + c1[c,p]*1                           (k=272)
// i.e. a K=273 (padded 288 = 9*32) matmul t = y @ coeff^T run on
// mfma_f32_16x16x32_bf16 with M=nodes, N=p(16), K=288.
// coeff is precomputed per channel in B-fragment order (bf16).

#define B_NODES 4096
#define C_CH    256
#define I_DIM   16
#define K3      23
#define K2      4

#define KSTEPS   9
#define KB_ELEMS (KSTEPS * 64 * 8)   // 4608 bf16 per channel

typedef short  short8 __attribute__((ext_vector_type(8)));
typedef float  f32x4  __attribute__((ext_vector_type(4)));

// ws layout (bytes): [bfrag: C*4608*2 = 2359296][sT: C*B*4 = 4 MiB]
static constexpr size_t OFF_BF_BYTES = 0;
static constexpr size_t OFF_ST_BYTES = (size_t)C_CH * KB_ELEMS * 2;  // 16B-aligned

__device__ inline unsigned short f2bf_rne(float f) {
  union { float f; unsigned u; } v; v.f = f;
  unsigned r = v.u + 0x7FFFu + ((v.u >> 16) & 1u);
  return (unsigned short)(r >> 16);
}
__device__ inline unsigned fbits(float f) {
  union { float f; unsigned u; } v; v.f = f; return v.u;
}

// ---------------------------------------------------------------------------
// Kernel 1: coeff[c][p][k] in bf16, laid out in MFMA B-fragment order:
//   element ((c*9 + step)*64 + lane)*8 + j  =  coeff[p=lane&15][k=step*32+(lane>>4)*8+j]
// k<256: U3.w3 contraction; 256<=k<272: U2.w2; k==272: U1.w1; else 0.
// ---------------------------------------------------------------------------
__global__ __launch_bounds__(256) void precompute_bfrag(
    const float* __restrict__ U3, const float* __restrict__ U2,
    const float* __restrict__ U1, const float* __restrict__ w3,
    const float* __restrict__ w2, const float* __restrict__ w1,
    unsigned int* __restrict__ bfrag_u32) {
  const int c = blockIdx.x, t = threadIdx.x;
  float w3r[K3], w2r[K2], w1r;
#pragma unroll
  for (int k = 0; k < K3; ++k) w3r[k] = w3[c * K3 + k];
#pragma unroll
  for (int k = 0; k < K2; ++k) w2r[k] = w2[c * K2 + k];
  w1r = w1[c];

  for (int pi = t; pi < KB_ELEMS / 2; pi += 256) {
    const int e0   = pi * 2;                  // even element index
    const int step = e0 >> 9;
    const int rem  = e0 & 511;
    const int lane = rem >> 3;
    const int jj   = rem & 7;                 // 0,2,4,6
    const int p    = lane & 15, g = lane >> 4;
    float v[2];
#pragma unroll
    for (int e = 0; e < 2; ++e) {
      const int k = step * 32 + g * 8 + jj + e;
      float a = 0.f;
      if (k < 256) {
        const int q = k >> 4, i = k & 15;
        const float* u = U3 + (size_t)((p * 16 + q) * 16 + i) * K3;
#pragma unroll
        for (int k3 = 0; k3 < K3; ++k3) a += u[k3] * w3r[k3];
      } else if (k < 272) {
        const int q = k - 256;
        const float* u = U2 + (size_t)(p * 16 + q) * K2;
#pragma unroll
        for (int k2 = 0; k2 < K2; ++k2) a += u[k2] * w2r[k2];
      } else if (k == 272) {
        a = U1[p] * w1r;
      }
      v[e] = a;
    }
    bfrag_u32[((size_t)c * KB_ELEMS + e0) >> 1] =
        (unsigned)f2bf_rne(v[0]) | ((unsigned)f2bf_rne(v[1]) << 16);
  }
}

// ---------------------------------------------------------------------------
// Kernel 2: MFMA contraction. Block = 256 thr (4 waves), covers 1 channel x
// 256 nodes (64/wave as 4 M-tiles of 16). Channel = blockIdx.x (fastest) so
// concurrent blocks read adjacent-c segments of the same cache lines.
// ---------------------------------------------------------------------------
#define SXS 20  // sx row stride (floats): 16B-aligned rows, 2-way-free banks

__global__ __launch_bounds__(256) void contract_mfma(
    const float* __restrict__ x, const short8* __restrict__ bfragv,
    float* __restrict__ sT) {
  const int c   = blockIdx.x;
  const int nb0 = blockIdx.y * 256;
  const int t   = threadIdx.x;
  const int w = t >> 6, lane = t & 63, n = lane & 15, g = lane >> 4;

  __shared__ float sx[256 * SXS];

  // B-fragments for all 9 K-steps: coalesced 16B loads, live in regs all kernel.
  short8 bf[KSTEPS];
  const short8* bp = bfragv + (size_t)c * (KSTEPS * 64);
#pragma unroll
  for (int s = 0; s < KSTEPS; ++s) bf[s] = bp[s * 64 + lane];

  // Stage x tile: thread t owns node nb0+t (16 floats = one 64B segment).
  {
    const float4* xg = (const float4*)(x + ((size_t)(nb0 + t) * C_CH + c) * I_DIM);
    float4 a0 = xg[0], a1 = xg[1], a2 = xg[2], a3 = xg[3];
    float* row = sx + t * SXS;
    *(float4*)(row + 0)  = a0; *(float4*)(row + 4)  = a1;
    *(float4*)(row + 8)  = a2; *(float4*)(row + 12) = a3;
  }
  __syncthreads();

  f32x4 acc[4];
#pragma unroll
  for (int T = 0; T < 4; ++T) acc[T] = (f32x4){0.f, 0.f, 0.f, 0.f};

  const bool ghi = (g & 1) != 0;        // i-half select: i0 = (g&1)*8
  const bool gq  = ((g >> 1) & 1) != 0; // q parity within step: q = 2s + (g>>1)

#pragma unroll
  for (int T = 0; T < 4; ++T) {
    // This lane's node for A-rows: m = n  -> node = nb0 + w*64 + T*16 + n.
    const float* xrow = sx + (size_t)(w * 64 + T * 16 + n) * SXS;
    float xr[16];
#pragma unroll
    for (int v4 = 0; v4 < 4; ++v4) {
      float4 vv = *(const float4*)(xrow + v4 * 4);
      xr[v4 * 4 + 0] = vv.x; xr[v4 * 4 + 1] = vv.y;
      xr[v4 * 4 + 2] = vv.z; xr[v4 * 4 + 3] = vv.w;
    }
    float xh[8];
#pragma unroll
    for (int j = 0; j < 8; ++j) xh[j] = ghi ? xr[8 + j] : xr[j];

    // Steps 0..7: pure quadratic rows  y[k] = x_q * x_i.
#pragma unroll
    for (int s = 0; s < 8; ++s) {
      const float xq = gq ? xr[s * 2 + 1] : xr[s * 2];
      union { unsigned u[4]; short8 v; } af;
#pragma unroll
      for (int m2 = 0; m2 < 4; ++m2) {
        const float y0 = xq * xh[m2 * 2];
        const float y1 = xq * xh[m2 * 2 + 1];
        af.u[m2] = __builtin_amdgcn_perm(fbits(y1), fbits(y0), 0x07060302u);
      }
      acc[T] = __builtin_amdgcn_mfma_f32_16x16x32_bf16(af.v, bf[s], acc[T], 0, 0, 0);
    }
    // Step 8: linear rows (k=256+q -> x_q), const row (k=272 -> 1), zero pad.
    {
      float y[8];
#pragma unroll
      for (int j = 0; j < 8; ++j)
        y[j] = (g == 0) ? xr[j] : ((g == 1) ? xr[8 + j] : 0.f);
      y[0] = (g == 2) ? 1.0f : y[0];
      union { unsigned u[4]; short8 v; } af;
#pragma unroll
      for (int m2 = 0; m2 < 4; ++m2)
        af.u[m2] = __builtin_amdgcn_perm(fbits(y[m2 * 2 + 1]), fbits(y[m2 * 2]), 0x07060302u);
      acc[T] = __builtin_amdgcn_mfma_f32_16x16x32_bf16(af.v, bf[8], acc[T], 0, 0, 0);
    }
  }

  // Epilogue: s[node] = sum_p x[node][p] * t[node][p].
  // D layout: col p = lane&15 (=n), row = g*4 + r  ->  node = base + T*16 + g*4 + r.
#pragma unroll
  for (int T = 0; T < 4; ++T) {
    float v[4];
#pragma unroll
    for (int r = 0; r < 4; ++r) {
      const int nodeL = w * 64 + T * 16 + g * 4 + r;
      v[r] = acc[T][r] * sx[(size_t)nodeL * SXS + n];
    }
#pragma unroll
    for (int mask = 1; mask <= 8; mask <<= 1) {
#pragma unroll
      for (int r = 0; r < 4; ++r) v[r] += __shfl_xor(v[r], mask);
    }
    if (n == 0) {
      *(float4*)(sT + (size_t)c * B_NODES + nb0 + w * 64 + T * 16 + g * 4) =
          make_float4(v[0], v[1], v[2], v[3]);
    }
  }
}

// ---------------------------------------------------------------------------
// Kernel 3: out[b,d] = (1/16) * sum_c sT[c,b] * W[c,d]  (fp32, 64x64 tiles)
// ---------------------------------------------------------------------------
__global__ __launch_bounds__(256) void linear_kernel(
    const float* __restrict__ sT, const float* __restrict__ W,
    float* __restrict__ out) {
  const int b0 = blockIdx.x * 64;
  const int d0 = blockIdx.y * 64;
  const int t  = threadIdx.x;
  const int tx = t & 15;
  const int ty = t >> 4;

  __shared__ float As[16][64];
  __shared__ float Bs[16][64];
  float acc[4][4] = {};

  for (int k0 = 0; k0 < C_CH; k0 += 16) {
    const int kk  = t >> 6;
    const int col = t & 63;
#pragma unroll
    for (int r = 0; r < 4; ++r) {
      As[kk + r * 4][col] = sT[(size_t)(k0 + kk + r * 4) * B_NODES + b0 + col];
      Bs[kk + r * 4][col] = W[(size_t)(k0 + kk + r * 4) * C_CH + d0 + col];
    }
    __syncthreads();
#pragma unroll
    for (int k = 0; k < 16; ++k) {
      float a[4], bv[4];
#pragma unroll
      for (int i = 0; i < 4; ++i) a[i] = As[k][ty * 4 + i];
#pragma unroll
      for (int j = 0; j < 4; ++j) bv[j] = Bs[k][tx * 4 + j];
#pragma unroll
      for (int i = 0; i < 4; ++i)
#pragma unroll
        for (int j = 0; j < 4; ++j) acc[i][j] += a[i] * bv[j];
    }
    __syncthreads();
  }

#pragma unroll
  for (int i = 0; i < 4; ++i) {
    float4 v = make_float4(acc[i][0] * 0.0625f, acc[i][1] * 0.0625f,
                           acc[i][2] * 0.0625f, acc[i][3] * 0.0625f);
    *(float4*)(out + (size_t)(b0 + ty * 4 + i) * C_CH + d0 + tx * 4) = v;
  }
}

extern "C" void kernel_launch(void* const* d_in, const int* in_sizes, int n_in,
                              void* d_out, int out_size, void* d_ws, size_t ws_size,
                              hipStream_t stream) {
  const float* x  = (const float*)d_in[0];
  const float* U3 = (const float*)d_in[1];
  const float* U2 = (const float*)d_in[2];
  const float* U1 = (const float*)d_in[3];
  const float* w3 = (const float*)d_in[4];
  const float* w2 = (const float*)d_in[5];
  const float* w1 = (const float*)d_in[6];
  const float* Wl = (const float*)d_in[7];

  unsigned int* bfrag = (unsigned int*)((char*)d_ws + OFF_BF_BYTES);
  float*        sT    = (float*)((char*)d_ws + OFF_ST_BYTES);
  float*        out   = (float*)d_out;

  precompute_bfrag<<<dim3(C_CH), dim3(256), 0, stream>>>(U3, U2, U1, w3, w2, w1, bfrag);
  contract_mfma<<<dim3(C_CH, B_NODES / 256), dim3(256), 0, stream>>>(
      x, (const short8*)bfrag, sT);
  linear_kernel<<<dim3(B_NODES / 64, C_CH / 64), dim3(256), 0, stream>>>(sT, Wl, out);
}

// Round 3
// 196.031 us; speedup vs baseline: 1.5880x; 1.1165x over previous
//
#include <hip/hip_runtime.h>

// MACE symmetric contraction, B=4096 nodes, C=256 channels, I=16.
//
// Per (b,c):  s[b,c] = sum_p x_p * t[b,p],
//   t[b,p] = sum_{k<256} U3w[c,p,q,i]*x_q*x_i   (k=q*16+i)
//          + sum_q c2[c,p,q]*x_q (k=256+q)  +  c1[c,p] (k=272)
// => K=273 (pad 288=9*32) matmul on mfma_f32_16x16x32_bf16, M=nodes, N=p.
// coeff precomputed per channel in MFMA B-fragment order (bf16).

#define B_NODES 4096
#define C_CH    256
#define K3      23
#define K2      4

#define KSTEPS   9
#define KB_ELEMS (KSTEPS * 64 * 8)   // 4608 bf16 per channel

typedef short  short8 __attribute__((ext_vector_type(8)));
typedef float  f32x4  __attribute__((ext_vector_type(4)));

// ws layout (bytes): [bfrag: C*4608*2][sT: C*B*4]
static constexpr size_t OFF_BF_BYTES = 0;
static constexpr size_t OFF_ST_BYTES = (size_t)C_CH * KB_ELEMS * 2;

__device__ inline unsigned short f2bf_rne(float f) {
  union { float f; unsigned u; } v; v.f = f;
  unsigned r = v.u + 0x7FFFu + ((v.u >> 16) & 1u);
  return (unsigned short)(r >> 16);
}
__device__ inline unsigned fbits(float f) {
  union { float f; unsigned u; } v; v.f = f; return v.u;
}

// ---------------------------------------------------------------------------
// Kernel 1: coeff in B-fragment order. grid (9 steps, 32 channel-groups of 8).
// Steps 0..7 stage a 47 KB U3 slice (the step's 2 q-values, all p,i) in LDS
// ONCE per block and compute 8 channels from it -> U3 HBM/L3 traffic ~14 MB
// instead of 384 MB (previous per-channel-block version).
// Element mapping: bfrag[((c*9+s)*64+lane)*8+j] = coeff[p=lane&15][k=s*32+(lane>>4)*8+j]
// ---------------------------------------------------------------------------
__global__ __launch_bounds__(256) void precompute_bfrag(
    const float* __restrict__ U3, const float* __restrict__ U2,
    const float* __restrict__ U1, const float* __restrict__ w3,
    const float* __restrict__ w2, const float* __restrict__ w1,
    unsigned int* __restrict__ bfrag_u32) {
  const int s  = blockIdx.x;        // K-step 0..8
  const int c0 = blockIdx.y * 8;    // 8 channels per block
  const int t  = threadIdx.x;
  // thread t owns u32 index (s*256 + t) of each channel => elements e0=2t, 2t+1
  const int lane = t >> 2;          // fragment lane
  const int jj   = (t & 3) * 2;     // 0,2,4,6
  const int p = lane & 15, g = lane >> 4;

  __shared__ float su3[512 * 23];   // rows: p*32 + qb*16 + i

  if (s < 8) {
    for (int l = t; l < 512 * 23; l += 256) {
      const int row = l / 23, col = l - row * 23;
      const int pp = row >> 5, qb = (row >> 4) & 1, ii = row & 15;
      su3[l] = U3[(size_t)((pp * 16 + (2 * s + qb)) * 16 + ii) * K3 + col];
    }
    __syncthreads();

    // this thread's two coefficient rows (k = s*32+g*8+jj+{0,1})
    const int r0 = p * 32 + (g >> 1) * 16 + (g & 1) * 8 + jj;
    float u0[K3], u1[K3];
#pragma unroll
    for (int k3 = 0; k3 < K3; ++k3) {
      u0[k3] = su3[(size_t)r0 * K3 + k3];
      u1[k3] = su3[(size_t)(r0 + 1) * K3 + k3];
    }
#pragma unroll
    for (int ch = 0; ch < 8; ++ch) {
      const int c = c0 + ch;
      float a0 = 0.f, a1 = 0.f;
#pragma unroll
      for (int k3 = 0; k3 < K3; ++k3) {
        const float wv = w3[c * K3 + k3];   // uniform -> scalar load
        a0 += u0[k3] * wv;
        a1 += u1[k3] * wv;
      }
      bfrag_u32[(size_t)c * (KB_ELEMS / 2) + s * 256 + t] =
          (unsigned)f2bf_rne(a0) | ((unsigned)f2bf_rne(a1) << 16);
    }
  } else {
    // s == 8: k in [256,288): linear rows (x_q), constant row (k==272), pad 0.
#pragma unroll
    for (int ch = 0; ch < 8; ++ch) {
      const int c = c0 + ch;
      float v[2] = {0.f, 0.f};
#pragma unroll
      for (int e = 0; e < 2; ++e) {
        const int k = 256 + g * 8 + jj + e;
        if (k < 272) {
          const int q = k - 256;
          float a = 0.f;
#pragma unroll
          for (int k2 = 0; k2 < K2; ++k2)
            a += U2[(size_t)(p * 16 + q) * K2 + k2] * w2[c * K2 + k2];
          v[e] = a;
        } else if (k == 272) {
          v[e] = U1[p] * w1[c];
        }
      }
      bfrag_u32[(size_t)c * (KB_ELEMS / 2) + s * 256 + t] =
          (unsigned)f2bf_rne(v[0]) | ((unsigned)f2bf_rne(v[1]) << 16);
    }
  }
}

// ---------------------------------------------------------------------------
// Kernel 2: MFMA contraction. Block = 256 thr (4 waves) = 1 channel x 256
// nodes (4 M-tiles of 16 per wave). Channel = blockIdx.x (fastest) so
// concurrent blocks share x cache lines.
// K-step loop OUTERMOST; only derived per-lane x values (xh, xqs) live across
// it -> ~130 VGPRs, no scratch spills (R2's 44-VGPR + 200 MB scratch WRITE).
// __launch_bounds__(256,3): allow ~170 VGPRs (3 waves/EU = 3 blocks/CU).
// ---------------------------------------------------------------------------
#define SXS 20  // sx row stride (floats): 16B-aligned, 2-way-free banks

__global__ __launch_bounds__(256, 3) void contract_mfma(
    const float* __restrict__ x, const short8* __restrict__ bfragv,
    float* __restrict__ sT) {
  const int c   = blockIdx.x;
  const int nb0 = blockIdx.y * 256;
  const int t   = threadIdx.x;
  const int w = t >> 6, lane = t & 63, n = lane & 15, g = lane >> 4;

  __shared__ float sx[256 * SXS];

  // B-fragments for all 9 K-steps (36 VGPRs, live all kernel — intended).
  short8 bf[KSTEPS];
  const short8* bp = bfragv + (size_t)c * (KSTEPS * 64);
#pragma unroll
  for (int s = 0; s < KSTEPS; ++s) bf[s] = bp[s * 64 + lane];

  // Stage x tile: thread t owns node nb0+t (16 floats = one 64B segment).
  {
    const float4* xg = (const float4*)(x + ((size_t)(nb0 + t) * C_CH + c) * 16);
    float4 a0 = xg[0], a1 = xg[1], a2 = xg[2], a3 = xg[3];
    float* row = sx + t * SXS;
    *(float4*)(row + 0)  = a0; *(float4*)(row + 4)  = a1;
    *(float4*)(row + 8)  = a2; *(float4*)(row + 12) = a3;
  }
  __syncthreads();

  const bool ghi = (g & 1) != 0;        // i-half: i = (g&1)*8 + j
  const bool gq  = ((g >> 1) & 1) != 0; // q = 2s + (g>>1)

  // Pre-derive per-lane x values for all 4 M-tiles (64 VGPRs).
  float xh[4][8];   // xh[T][j]  = x[i-half selected by g]
  float xqs[4][8];  // xqs[T][s] = x[2s + (g>>1)]
#pragma unroll
  for (int T = 0; T < 4; ++T) {
    const float* xrow = sx + (size_t)(w * 64 + T * 16 + n) * SXS;
    float xr[16];
#pragma unroll
    for (int v4 = 0; v4 < 4; ++v4) {
      float4 vv = *(const float4*)(xrow + v4 * 4);
      xr[v4 * 4 + 0] = vv.x; xr[v4 * 4 + 1] = vv.y;
      xr[v4 * 4 + 2] = vv.z; xr[v4 * 4 + 3] = vv.w;
    }
#pragma unroll
    for (int j = 0; j < 8; ++j) xh[T][j] = ghi ? xr[8 + j] : xr[j];
#pragma unroll
    for (int s = 0; s < 8; ++s) xqs[T][s] = gq ? xr[2 * s + 1] : xr[2 * s];
  }

  f32x4 acc[4];
#pragma unroll
  for (int T = 0; T < 4; ++T) acc[T] = (f32x4){0.f, 0.f, 0.f, 0.f};

  // Steps 0..7: quadratic rows y[k] = x_q * x_i.
#pragma unroll
  for (int s = 0; s < 8; ++s) {
#pragma unroll
    for (int T = 0; T < 4; ++T) {
      union { unsigned u[4]; short8 v; } af;
#pragma unroll
      for (int m2 = 0; m2 < 4; ++m2) {
        const float y0 = xqs[T][s] * xh[T][m2 * 2];
        const float y1 = xqs[T][s] * xh[T][m2 * 2 + 1];
        af.u[m2] = __builtin_amdgcn_perm(fbits(y1), fbits(y0), 0x07060302u);
      }
      acc[T] = __builtin_amdgcn_mfma_f32_16x16x32_bf16(af.v, bf[s], acc[T], 0, 0, 0);
    }
  }
  // Step 8: linear rows (g<2 -> x half, matches ghi), const-1 row (g==2,j==0).
#pragma unroll
  for (int T = 0; T < 4; ++T) {
    float y[8];
#pragma unroll
    for (int j = 0; j < 8; ++j) y[j] = (g < 2) ? xh[T][j] : 0.f;
    y[0] = (g == 2) ? 1.0f : y[0];
    union { unsigned u[4]; short8 v; } af;
#pragma unroll
    for (int m2 = 0; m2 < 4; ++m2)
      af.u[m2] = __builtin_amdgcn_perm(fbits(y[m2 * 2 + 1]), fbits(y[m2 * 2]), 0x07060302u);
    acc[T] = __builtin_amdgcn_mfma_f32_16x16x32_bf16(af.v, bf[8], acc[T], 0, 0, 0);
  }

  // Epilogue: s[node] = sum_p x[node][p] * t[node][p].
  // D layout: col p = lane&15 (=n), row = g*4 + r.
#pragma unroll
  for (int T = 0; T < 4; ++T) {
    float v[4];
#pragma unroll
    for (int r = 0; r < 4; ++r) {
      const int nodeL = w * 64 + T * 16 + g * 4 + r;
      v[r] = acc[T][r] * sx[(size_t)nodeL * SXS + n];
    }
#pragma unroll
    for (int mask = 1; mask <= 8; mask <<= 1) {
#pragma unroll
      for (int r = 0; r < 4; ++r) v[r] += __shfl_xor(v[r], mask);
    }
    if (n == 0) {
      *(float4*)(sT + (size_t)c * B_NODES + nb0 + w * 64 + T * 16 + g * 4) =
          make_float4(v[0], v[1], v[2], v[3]);
    }
  }
}

// ---------------------------------------------------------------------------
// Kernel 3: out[b,d] = (1/16) * sum_c sT[c,b] * W[c,d]  (fp32, 64x64 tiles)
// ---------------------------------------------------------------------------
__global__ __launch_bounds__(256) void linear_kernel(
    const float* __restrict__ sT, const float* __restrict__ W,
    float* __restrict__ out) {
  const int b0 = blockIdx.x * 64;
  const int d0 = blockIdx.y * 64;
  const int t  = threadIdx.x;
  const int tx = t & 15;
  const int ty = t >> 4;

  __shared__ float As[16][64];
  __shared__ float Bs[16][64];
  float acc[4][4] = {};

  for (int k0 = 0; k0 < C_CH; k0 += 16) {
    const int kk  = t >> 6;
    const int col = t & 63;
#pragma unroll
    for (int r = 0; r < 4; ++r) {
      As[kk + r * 4][col] = sT[(size_t)(k0 + kk + r * 4) * B_NODES + b0 + col];
      Bs[kk + r * 4][col] = W[(size_t)(k0 + kk + r * 4) * C_CH + d0 + col];
    }
    __syncthreads();
#pragma unroll
    for (int k = 0; k < 16; ++k) {
      float a[4], bv[4];
#pragma unroll
      for (int i = 0; i < 4; ++i) a[i] = As[k][ty * 4 + i];
#pragma unroll
      for (int j = 0; j < 4; ++j) bv[j] = Bs[k][tx * 4 + j];
#pragma unroll
      for (int i = 0; i < 4; ++i)
#pragma unroll
        for (int j = 0; j < 4; ++j) acc[i][j] += a[i] * bv[j];
    }
    __syncthreads();
  }

#pragma unroll
  for (int i = 0; i < 4; ++i) {
    float4 v = make_float4(acc[i][0] * 0.0625f, acc[i][1] * 0.0625f,
                           acc[i][2] * 0.0625f, acc[i][3] * 0.0625f);
    *(float4*)(out + (size_t)(b0 + ty * 4 + i) * C_CH + d0 + tx * 4) = v;
  }
}

extern "C" void kernel_launch(void* const* d_in, const int* in_sizes, int n_in,
                              void* d_out, int out_size, void* d_ws, size_t ws_size,
                              hipStream_t stream) {
  const float* x  = (const float*)d_in[0];
  const float* U3 = (const float*)d_in[1];
  const float* U2 = (const float*)d_in[2];
  const float* U1 = (const float*)d_in[3];
  const float* w3 = (const float*)d_in[4];
  const float* w2 = (const float*)d_in[5];
  const float* w1 = (const float*)d_in[6];
  const float* Wl = (const float*)d_in[7];

  unsigned int* bfrag = (unsigned int*)((char*)d_ws + OFF_BF_BYTES);
  float*        sT    = (float*)((char*)d_ws + OFF_ST_BYTES);
  float*        out   = (float*)d_out;

  precompute_bfrag<<<dim3(KSTEPS, C_CH / 8), dim3(256), 0, stream>>>(
      U3, U2, U1, w3, w2, w1, bfrag);
  contract_mfma<<<dim3(C_CH, B_NODES / 256), dim3(256), 0, stream>>>(
      x, (const short8*)bfrag, sT);
  linear_kernel<<<dim3(B_NODES / 64, C_CH / 64), dim3(256), 0, stream>>>(sT, Wl, out);
}

// Round 4
// 195.284 us; speedup vs baseline: 1.5941x; 1.0038x over previous
//
#include <hip/hip_runtime.h>

// MACE symmetric contraction, B=4096 nodes, C=256 channels, I=16.
//
// Per (b,c):  s[b,c] = sum_p x_p * t[b,p],
//   t[b,p] = sum_{k<256} U3w[c,p,q,i]*x_q*x_i   (k=q*16+i)
//          + sum_q c2[c,p,q]*x_q (k=256+q)  +  c1[c,p] (k=272)
// => K=273 (pad 288=9*32) matmul on mfma_f32_16x16x32_bf16, M=nodes, N=p.
// coeff precomputed per channel in MFMA B-fragment order (bf16).

#define B_NODES 4096
#define C_CH    256
#define K3      23
#define K2      4

#define KSTEPS   9
#define KB_ELEMS (KSTEPS * 64 * 8)   // 4608 bf16 per channel
#define KB_U32   (KB_ELEMS / 2)      // 2304 u32 per channel

typedef short  short8 __attribute__((ext_vector_type(8)));
typedef float  f32x4  __attribute__((ext_vector_type(4)));

// ws layout (bytes): [bfrag: C*4608*2][sT: C*B*4]
static constexpr size_t OFF_BF_BYTES = 0;
static constexpr size_t OFF_ST_BYTES = (size_t)C_CH * KB_ELEMS * 2;

__device__ inline unsigned short f2bf_rne(float f) {
  union { float f; unsigned u; } v; v.f = f;
  unsigned r = v.u + 0x7FFFu + ((v.u >> 16) & 1u);
  return (unsigned short)(r >> 16);
}
__device__ inline unsigned fbits(float f) {
  union { float f; unsigned u; } v; v.f = f; return v.u;
}

// ---------------------------------------------------------------------------
// Kernel 1: coeff in B-fragment order. grid (9 steps, 32 channel-groups of 8).
// Steps 0..7 stage a 47 KB U3 slice (the step's 2 q-values, all p,i) in LDS
// once per block and compute 8 channels from it.
// Mapping: bfrag[((c*9+s)*64+lane)*8+j] = coeff[p=lane&15][k=s*32+(lane>>4)*8+j]
// ---------------------------------------------------------------------------
__global__ __launch_bounds__(256) void precompute_bfrag(
    const float* __restrict__ U3, const float* __restrict__ U2,
    const float* __restrict__ U1, const float* __restrict__ w3,
    const float* __restrict__ w2, const float* __restrict__ w1,
    unsigned int* __restrict__ bfrag_u32) {
  const int s  = blockIdx.x;        // K-step 0..8
  const int c0 = blockIdx.y * 8;    // 8 channels per block
  const int t  = threadIdx.x;
  const int lane = t >> 2;          // fragment lane
  const int jj   = (t & 3) * 2;     // 0,2,4,6
  const int p = lane & 15, g = lane >> 4;

  __shared__ float su3[512 * 23];   // rows: p*32 + qb*16 + i

  if (s < 8) {
    for (int l = t; l < 512 * 23; l += 256) {
      const int row = l / 23, col = l - row * 23;
      const int pp = row >> 5, qb = (row >> 4) & 1, ii = row & 15;
      su3[l] = U3[(size_t)((pp * 16 + (2 * s + qb)) * 16 + ii) * K3 + col];
    }
    __syncthreads();

    const int r0 = p * 32 + (g >> 1) * 16 + (g & 1) * 8 + jj;
    float u0[K3], u1[K3];
#pragma unroll
    for (int k3 = 0; k3 < K3; ++k3) {
      u0[k3] = su3[(size_t)r0 * K3 + k3];
      u1[k3] = su3[(size_t)(r0 + 1) * K3 + k3];
    }
#pragma unroll
    for (int ch = 0; ch < 8; ++ch) {
      const int c = c0 + ch;
      float a0 = 0.f, a1 = 0.f;
#pragma unroll
      for (int k3 = 0; k3 < K3; ++k3) {
        const float wv = w3[c * K3 + k3];   // uniform -> scalar load
        a0 += u0[k3] * wv;
        a1 += u1[k3] * wv;
      }
      bfrag_u32[(size_t)c * KB_U32 + s * 256 + t] =
          (unsigned)f2bf_rne(a0) | ((unsigned)f2bf_rne(a1) << 16);
    }
  } else {
    // s == 8: linear rows (x_q), constant row (k==272), pad 0.
#pragma unroll
    for (int ch = 0; ch < 8; ++ch) {
      const int c = c0 + ch;
      float v[2] = {0.f, 0.f};
#pragma unroll
      for (int e = 0; e < 2; ++e) {
        const int k = 256 + g * 8 + jj + e;
        if (k < 272) {
          const int q = k - 256;
          float a = 0.f;
#pragma unroll
          for (int k2 = 0; k2 < K2; ++k2)
            a += U2[(size_t)(p * 16 + q) * K2 + k2] * w2[c * K2 + k2];
          v[e] = a;
        } else if (k == 272) {
          v[e] = U1[p] * w1[c];
        }
      }
      bfrag_u32[(size_t)c * KB_U32 + s * 256 + t] =
          (unsigned)f2bf_rne(v[0]) | ((unsigned)f2bf_rne(v[1]) << 16);
    }
  }
}

// ---------------------------------------------------------------------------
// Kernel 2: MFMA contraction. Block = 256 thr (4 waves) = 1 channel x 256
// nodes. Channel = blockIdx.x (fastest) so concurrent blocks share x lines.
//
// R4 spill fix: coeff fragments live in LDS (staged coalesced once/block,
// 9216 B) and are ds_read_b128 per K-step right before use — no kernel-long
// single-use registers for the RA to spill. amdgpu_waves_per_eu(2,4) caps
// occupancy-chasing (R3: RA spilled 64 B/thread to reach 7 waves/EU).
// ---------------------------------------------------------------------------
#define SXS 20  // sx row stride (floats): 16B-aligned, 2-way-free banks

__global__ __launch_bounds__(256)
__attribute__((amdgpu_waves_per_eu(2, 4)))
void contract_mfma(
    const float* __restrict__ x, const unsigned int* __restrict__ bfrag_u32,
    float* __restrict__ sT) {
  const int c   = blockIdx.x;
  const int nb0 = blockIdx.y * 256;
  const int t   = threadIdx.x;
  const int w = t >> 6, lane = t & 63, n = lane & 15, g = lane >> 4;

  __shared__ float sx[256 * SXS];
  __shared__ unsigned int sbf[KB_U32];   // 9216 B: coeff fragments, all 9 steps

  // Stage coeff: 9 coalesced u32 per thread.
  {
    const unsigned int* bp = bfrag_u32 + (size_t)c * KB_U32;
#pragma unroll
    for (int i = 0; i < KSTEPS; ++i) sbf[i * 256 + t] = bp[i * 256 + t];
  }
  // Stage x tile: thread t owns node nb0+t (16 floats = one 64B segment).
  {
    const float4* xg = (const float4*)(x + ((size_t)(nb0 + t) * C_CH + c) * 16);
    float4 a0 = xg[0], a1 = xg[1], a2 = xg[2], a3 = xg[3];
    float* row = sx + t * SXS;
    *(float4*)(row + 0)  = a0; *(float4*)(row + 4)  = a1;
    *(float4*)(row + 8)  = a2; *(float4*)(row + 12) = a3;
  }
  __syncthreads();

  const bool ghi = (g & 1) != 0;        // i-half: i = (g&1)*8 + j
  const bool gq  = ((g >> 1) & 1) != 0; // q = 2s + (g>>1)
  const short8* sbfv = (const short8*)sbf;

  f32x4 acc[4];
#pragma unroll
  for (int T = 0; T < 4; ++T) acc[T] = (f32x4){0.f, 0.f, 0.f, 0.f};

#pragma unroll
  for (int T = 0; T < 4; ++T) {
    // This lane's node for A-rows: m = n -> node = nb0 + w*64 + T*16 + n.
    const float* xrow = sx + (size_t)(w * 64 + T * 16 + n) * SXS;
    float xr[16];
#pragma unroll
    for (int v4 = 0; v4 < 4; ++v4) {
      float4 vv = *(const float4*)(xrow + v4 * 4);
      xr[v4 * 4 + 0] = vv.x; xr[v4 * 4 + 1] = vv.y;
      xr[v4 * 4 + 2] = vv.z; xr[v4 * 4 + 3] = vv.w;
    }
    float xh[8], xqs[8];
#pragma unroll
    for (int j = 0; j < 8; ++j) xh[j] = ghi ? xr[8 + j] : xr[j];
#pragma unroll
    for (int s = 0; s < 8; ++s) xqs[s] = gq ? xr[2 * s + 1] : xr[2 * s];

    // Steps 0..7: quadratic rows y[k] = x_q * x_i.
#pragma unroll
    for (int s = 0; s < 8; ++s) {
      const short8 bf = sbfv[s * 64 + lane];   // ds_read_b128, just-in-time
      union { unsigned u[4]; short8 v; } af;
#pragma unroll
      for (int m2 = 0; m2 < 4; ++m2) {
        const float y0 = xqs[s] * xh[m2 * 2];
        const float y1 = xqs[s] * xh[m2 * 2 + 1];
        af.u[m2] = __builtin_amdgcn_perm(fbits(y1), fbits(y0), 0x07060302u);
      }
      acc[T] = __builtin_amdgcn_mfma_f32_16x16x32_bf16(af.v, bf, acc[T], 0, 0, 0);
    }
    // Step 8: linear rows (g<2 -> x half, matches ghi), const-1 (g==2,j==0).
    {
      const short8 bf = sbfv[8 * 64 + lane];
      float y[8];
#pragma unroll
      for (int j = 0; j < 8; ++j) y[j] = (g < 2) ? xh[j] : 0.f;
      y[0] = (g == 2) ? 1.0f : y[0];
      union { unsigned u[4]; short8 v; } af;
#pragma unroll
      for (int m2 = 0; m2 < 4; ++m2)
        af.u[m2] = __builtin_amdgcn_perm(fbits(y[m2 * 2 + 1]), fbits(y[m2 * 2]), 0x07060302u);
      acc[T] = __builtin_amdgcn_mfma_f32_16x16x32_bf16(af.v, bf, acc[T], 0, 0, 0);
    }
  }

  // Epilogue: s[node] = sum_p x[node][p] * t[node][p].
  // D layout: col p = lane&15 (=n), row = g*4 + r.
#pragma unroll
  for (int T = 0; T < 4; ++T) {
    float v[4];
#pragma unroll
    for (int r = 0; r < 4; ++r) {
      const int nodeL = w * 64 + T * 16 + g * 4 + r;
      v[r] = acc[T][r] * sx[(size_t)nodeL * SXS + n];
    }
#pragma unroll
    for (int mask = 1; mask <= 8; mask <<= 1) {
#pragma unroll
      for (int r = 0; r < 4; ++r) v[r] += __shfl_xor(v[r], mask);
    }
    if (n == 0) {
      *(float4*)(sT + (size_t)c * B_NODES + nb0 + w * 64 + T * 16 + g * 4) =
          make_float4(v[0], v[1], v[2], v[3]);
    }
  }
}

// ---------------------------------------------------------------------------
// Kernel 3: out[b,d] = (1/16) * sum_c sT[c,b] * W[c,d]  (fp32, 64x64 tiles)
// ---------------------------------------------------------------------------
__global__ __launch_bounds__(256) void linear_kernel(
    const float* __restrict__ sT, const float* __restrict__ W,
    float* __restrict__ out) {
  const int b0 = blockIdx.x * 64;
  const int d0 = blockIdx.y * 64;
  const int t  = threadIdx.x;
  const int tx = t & 15;
  const int ty = t >> 4;

  __shared__ float As[16][64];
  __shared__ float Bs[16][64];
  float acc[4][4] = {};

  for (int k0 = 0; k0 < C_CH; k0 += 16) {
    const int kk  = t >> 6;
    const int col = t & 63;
#pragma unroll
    for (int r = 0; r < 4; ++r) {
      As[kk + r * 4][col] = sT[(size_t)(k0 + kk + r * 4) * B_NODES + b0 + col];
      Bs[kk + r * 4][col] = W[(size_t)(k0 + kk + r * 4) * C_CH + d0 + col];
    }
    __syncthreads();
#pragma unroll
    for (int k = 0; k < 16; ++k) {
      float a[4], bv[4];
#pragma unroll
      for (int i = 0; i < 4; ++i) a[i] = As[k][ty * 4 + i];
#pragma unroll
      for (int j = 0; j < 4; ++j) bv[j] = Bs[k][tx * 4 + j];
#pragma unroll
      for (int i = 0; i < 4; ++i)
#pragma unroll
        for (int j = 0; j < 4; ++j) acc[i][j] += a[i] * bv[j];
    }
    __syncthreads();
  }

#pragma unroll
  for (int i = 0; i < 4; ++i) {
    float4 v = make_float4(acc[i][0] * 0.0625f, acc[i][1] * 0.0625f,
                           acc[i][2] * 0.0625f, acc[i][3] * 0.0625f);
    *(float4*)(out + (size_t)(b0 + ty * 4 + i) * C_CH + d0 + tx * 4) = v;
  }
}

extern "C" void kernel_launch(void* const* d_in, const int* in_sizes, int n_in,
                              void* d_out, int out_size, void* d_ws, size_t ws_size,
                              hipStream_t stream) {
  const float* x  = (const float*)d_in[0];
  const float* U3 = (const float*)d_in[1];
  const float* U2 = (const float*)d_in[2];
  const float* U1 = (const float*)d_in[3];
  const float* w3 = (const float*)d_in[4];
  const float* w2 = (const float*)d_in[5];
  const float* w1 = (const float*)d_in[6];
  const float* Wl = (const float*)d_in[7];

  unsigned int* bfrag = (unsigned int*)((char*)d_ws + OFF_BF_BYTES);
  float*        sT    = (float*)((char*)d_ws + OFF_ST_BYTES);
  float*        out   = (float*)d_out;

  precompute_bfrag<<<dim3(KSTEPS, C_CH / 8), dim3(256), 0, stream>>>(
      U3, U2, U1, w3, w2, w1, bfrag);
  contract_mfma<<<dim3(C_CH, B_NODES / 256), dim3(256), 0, stream>>>(
      x, bfrag, sT);
  linear_kernel<<<dim3(B_NODES / 64, C_CH / 64), dim3(256), 0, stream>>>(sT, Wl, out);
}

// Round 6
// 180.799 us; speedup vs baseline: 1.7218x; 1.0801x over previous
//
#include <hip/hip_runtime.h>

// MACE symmetric contraction, B=4096 nodes, C=256 channels, I=16.
//
// Per (b,c):  s[b,c] = sum_p x_p * t[b,p],
//   t[b,p] = sum_{k<256} U3w[c,p,q,i]*x_q*x_i   (k=q*16+i)
//          + sum_q c2[c,p,q]*x_q (k=256+q)  +  c1[c,p] (k=272)
// => K=273 (pad 288=9*32) matmul on mfma_f32_16x16x32_bf16, M=nodes, N=p.
// coeff precomputed per channel in MFMA B-fragment order (bf16).
//
// R6: R5 with the staging-loop round count fixed (was 2, must be 8 — nodes
// 32..127 were computed from uninitialized LDS -> NaN).
// Block = 4 channels x 128 nodes, wave <-> channel. x staged via
// 256B-contiguous chunks (x[b] is contiguous across channels) -> coalesced.
// NOTE: ~110 us of total dur_us is fixed harness restore/poison overhead
// (constant across R1-R4); contract is the optimization target.

#define B_NODES 4096
#define C_CH    256
#define K3      23
#define K2      4

#define KSTEPS   9
#define KB_ELEMS (KSTEPS * 64 * 8)   // 4608 bf16 per channel
#define KB_U32   (KB_ELEMS / 2)      // 2304 u32 per channel

#define NODES_PER_BLK 128
#define SXS 68   // sx row stride in floats (64 data + 4 pad): 2-way-max banks

typedef short  short8 __attribute__((ext_vector_type(8)));
typedef float  f32x4  __attribute__((ext_vector_type(4)));

// ws layout (bytes): [bfrag: C*4608*2][sT: C*B*4]
static constexpr size_t OFF_BF_BYTES = 0;
static constexpr size_t OFF_ST_BYTES = (size_t)C_CH * KB_ELEMS * 2;

__device__ inline unsigned short f2bf_rne(float f) {
  union { float f; unsigned u; } v; v.f = f;
  unsigned r = v.u + 0x7FFFu + ((v.u >> 16) & 1u);
  return (unsigned short)(r >> 16);
}
__device__ inline unsigned fbits(float f) {
  union { float f; unsigned u; } v; v.f = f; return v.u;
}

// ---------------------------------------------------------------------------
// Kernel 1: coeff in B-fragment order. grid (9 steps, 32 channel-groups of 8).
// Mapping: bfrag[((c*9+s)*64+lane)*8+j] = coeff[p=lane&15][k=s*32+(lane>>4)*8+j]
// ---------------------------------------------------------------------------
__global__ __launch_bounds__(256) void precompute_bfrag(
    const float* __restrict__ U3, const float* __restrict__ U2,
    const float* __restrict__ U1, const float* __restrict__ w3,
    const float* __restrict__ w2, const float* __restrict__ w1,
    unsigned int* __restrict__ bfrag_u32) {
  const int s  = blockIdx.x;        // K-step 0..8
  const int c0 = blockIdx.y * 8;    // 8 channels per block
  const int t  = threadIdx.x;
  const int lane = t >> 2;          // fragment lane
  const int jj   = (t & 3) * 2;     // 0,2,4,6
  const int p = lane & 15, g = lane >> 4;

  __shared__ float su3[512 * 23];   // rows: p*32 + qb*16 + i

  if (s < 8) {
    for (int l = t; l < 512 * 23; l += 256) {
      const int row = l / 23, col = l - row * 23;
      const int pp = row >> 5, qb = (row >> 4) & 1, ii = row & 15;
      su3[l] = U3[(size_t)((pp * 16 + (2 * s + qb)) * 16 + ii) * K3 + col];
    }
    __syncthreads();

    const int r0 = p * 32 + (g >> 1) * 16 + (g & 1) * 8 + jj;
    float u0[K3], u1[K3];
#pragma unroll
    for (int k3 = 0; k3 < K3; ++k3) {
      u0[k3] = su3[(size_t)r0 * K3 + k3];
      u1[k3] = su3[(size_t)(r0 + 1) * K3 + k3];
    }
#pragma unroll
    for (int ch = 0; ch < 8; ++ch) {
      const int c = c0 + ch;
      float a0 = 0.f, a1 = 0.f;
#pragma unroll
      for (int k3 = 0; k3 < K3; ++k3) {
        const float wv = w3[c * K3 + k3];   // uniform -> scalar load
        a0 += u0[k3] * wv;
        a1 += u1[k3] * wv;
      }
      bfrag_u32[(size_t)c * KB_U32 + s * 256 + t] =
          (unsigned)f2bf_rne(a0) | ((unsigned)f2bf_rne(a1) << 16);
    }
  } else {
    // s == 8: linear rows (x_q), constant row (k==272), pad 0.
#pragma unroll
    for (int ch = 0; ch < 8; ++ch) {
      const int c = c0 + ch;
      float v[2] = {0.f, 0.f};
#pragma unroll
      for (int e = 0; e < 2; ++e) {
        const int k = 256 + g * 8 + jj + e;
        if (k < 272) {
          const int q = k - 256;
          float a = 0.f;
#pragma unroll
          for (int k2 = 0; k2 < K2; ++k2)
            a += U2[(size_t)(p * 16 + q) * K2 + k2] * w2[c * K2 + k2];
          v[e] = a;
        } else if (k == 272) {
          v[e] = U1[p] * w1[c];
        }
      }
      bfrag_u32[(size_t)c * KB_U32 + s * 256 + t] =
          (unsigned)f2bf_rne(v[0]) | ((unsigned)f2bf_rne(v[1]) << 16);
    }
  }
}

// ---------------------------------------------------------------------------
// Kernel 2: MFMA contraction. Block = 256 thr (4 waves); wave w owns channel
// c0+w; block covers 128 nodes. x staged as 256B-contiguous chunks
// (x[node][c0:c0+4][:]) -> fully coalesced. Coeff frags in regs per wave.
// ---------------------------------------------------------------------------
__global__ __launch_bounds__(256)
__attribute__((amdgpu_waves_per_eu(2, 4)))
void contract_mfma(
    const float* __restrict__ x, const short8* __restrict__ bfragv,
    float* __restrict__ sT) {
  const int c0  = blockIdx.x * 4;              // channel group (fastest)
  const int nb0 = blockIdx.y * NODES_PER_BLK;
  const int t   = threadIdx.x;
  const int w = t >> 6, lane = t & 63, n = lane & 15, g = lane >> 4;

  __shared__ float sx[NODES_PER_BLK * SXS];    // [node][4ch x 16 + pad]

  // Coeff fragments for this wave's channel: 9 coalesced dwordx4 -> 36 VGPRs.
  short8 bf[KSTEPS];
  {
    const short8* bp = bfragv + (size_t)(c0 + w) * (KSTEPS * 64);
#pragma unroll
    for (int s = 0; s < KSTEPS; ++s) bf[s] = bp[s * 64 + lane];
  }

  // Stage x: unit u = 16B chunk; node j = u>>4, sub = u&15.
  // Global: (nb0+j)*16KB + c0*64B + sub*16B  (256B contiguous per node).
  // 128 nodes * 16 chunks = 2048 chunks / 256 thr = 8 rounds.
#pragma unroll
  for (int r = 0; r < 8; ++r) {
    const int u = r * 256 + t;
    const int j = u >> 4, sub = u & 15;
    const float4 v = *(const float4*)(
        x + (size_t)(nb0 + j) * (C_CH * 16) + c0 * 16 + sub * 4);
    *(float4*)(sx + j * SXS + sub * 4) = v;
  }
  __syncthreads();

  const bool ghi = (g & 1) != 0;        // i-half: i = (g&1)*8 + j
  const bool gq  = ((g >> 1) & 1) != 0; // q = 2s + (g>>1)

  for (int T = 0; T < NODES_PER_BLK / 16; ++T) {   // 8 M-tiles of 16 nodes
    // A-rows: lane (n,g) needs node T*16+n, channel w -> row n, offset w*16.
    const float* xrow = sx + (size_t)(T * 16 + n) * SXS + w * 16;
    float xr[16];
#pragma unroll
    for (int v4 = 0; v4 < 4; ++v4) {
      float4 vv = *(const float4*)(xrow + v4 * 4);
      xr[v4 * 4 + 0] = vv.x; xr[v4 * 4 + 1] = vv.y;
      xr[v4 * 4 + 2] = vv.z; xr[v4 * 4 + 3] = vv.w;
    }
    float xh[8], xqs[8];
#pragma unroll
    for (int j = 0; j < 8; ++j) xh[j] = ghi ? xr[8 + j] : xr[j];
#pragma unroll
    for (int s = 0; s < 8; ++s) xqs[s] = gq ? xr[2 * s + 1] : xr[2 * s];

    f32x4 acc = (f32x4){0.f, 0.f, 0.f, 0.f};

    // Steps 0..7: quadratic rows y[k] = x_q * x_i.
#pragma unroll
    for (int s = 0; s < 8; ++s) {
      union { unsigned u[4]; short8 v; } af;
#pragma unroll
      for (int m2 = 0; m2 < 4; ++m2) {
        const float y0 = xqs[s] * xh[m2 * 2];
        const float y1 = xqs[s] * xh[m2 * 2 + 1];
        af.u[m2] = __builtin_amdgcn_perm(fbits(y1), fbits(y0), 0x07060302u);
      }
      acc = __builtin_amdgcn_mfma_f32_16x16x32_bf16(af.v, bf[s], acc, 0, 0, 0);
    }
    // Step 8: linear rows (g<2 -> x half, matches ghi), const-1 (g==2,j==0).
    {
      float y[8];
#pragma unroll
      for (int j = 0; j < 8; ++j) y[j] = (g < 2) ? xh[j] : 0.f;
      y[0] = (g == 2) ? 1.0f : y[0];
      union { unsigned u[4]; short8 v; } af;
#pragma unroll
      for (int m2 = 0; m2 < 4; ++m2)
        af.u[m2] = __builtin_amdgcn_perm(fbits(y[m2 * 2 + 1]), fbits(y[m2 * 2]), 0x07060302u);
      acc = __builtin_amdgcn_mfma_f32_16x16x32_bf16(af.v, bf[8], acc, 0, 0, 0);
    }

    // Epilogue for this tile: s[node] = sum_p x[node][p] * t[node][p].
    // D layout: col p = lane&15 (=n), row = g*4 + r.
    float v[4];
#pragma unroll
    for (int r = 0; r < 4; ++r) {
      const int row = T * 16 + g * 4 + r;
      v[r] = acc[r] * sx[(size_t)row * SXS + w * 16 + n];
    }
#pragma unroll
    for (int mask = 1; mask <= 8; mask <<= 1) {
#pragma unroll
      for (int r = 0; r < 4; ++r) v[r] += __shfl_xor(v[r], mask);
    }
    if (n == 0) {
      *(float4*)(sT + (size_t)(c0 + w) * B_NODES + nb0 + T * 16 + g * 4) =
          make_float4(v[0], v[1], v[2], v[3]);
    }
  }
}

// ---------------------------------------------------------------------------
// Kernel 3: out[b,d] = (1/16) * sum_c sT[c,b] * W[c,d]  (fp32, 64x64 tiles)
// ---------------------------------------------------------------------------
__global__ __launch_bounds__(256) void linear_kernel(
    const float* __restrict__ sT, const float* __restrict__ W,
    float* __restrict__ out) {
  const int b0 = blockIdx.x * 64;
  const int d0 = blockIdx.y * 64;
  const int t  = threadIdx.x;
  const int tx = t & 15;
  const int ty = t >> 4;

  __shared__ float As[16][64];
  __shared__ float Bs[16][64];
  float acc[4][4] = {};

  for (int k0 = 0; k0 < C_CH; k0 += 16) {
    const int kk  = t >> 6;
    const int col = t & 63;
#pragma unroll
    for (int r = 0; r < 4; ++r) {
      As[kk + r * 4][col] = sT[(size_t)(k0 + kk + r * 4) * B_NODES + b0 + col];
      Bs[kk + r * 4][col] = W[(size_t)(k0 + kk + r * 4) * C_CH + d0 + col];
    }
    __syncthreads();
#pragma unroll
    for (int k = 0; k < 16; ++k) {
      float a[4], bv[4];
#pragma unroll
      for (int i = 0; i < 4; ++i) a[i] = As[k][ty * 4 + i];
#pragma unroll
      for (int j = 0; j < 4; ++j) bv[j] = Bs[k][tx * 4 + j];
#pragma unroll
      for (int i = 0; i < 4; ++i)
#pragma unroll
        for (int j = 0; j < 4; ++j) acc[i][j] += a[i] * bv[j];
    }
    __syncthreads();
  }

#pragma unroll
  for (int i = 0; i < 4; ++i) {
    float4 v = make_float4(acc[i][0] * 0.0625f, acc[i][1] * 0.0625f,
                           acc[i][2] * 0.0625f, acc[i][3] * 0.0625f);
    *(float4*)(out + (size_t)(b0 + ty * 4 + i) * C_CH + d0 + tx * 4) = v;
  }
}

extern "C" void kernel_launch(void* const* d_in, const int* in_sizes, int n_in,
                              void* d_out, int out_size, void* d_ws, size_t ws_size,
                              hipStream_t stream) {
  const float* x  = (const float*)d_in[0];
  const float* U3 = (const float*)d_in[1];
  const float* U2 = (const float*)d_in[2];
  const float* U1 = (const float*)d_in[3];
  const float* w3 = (const float*)d_in[4];
  const float* w2 = (const float*)d_in[5];
  const float* w1 = (const float*)d_in[6];
  const float* Wl = (const float*)d_in[7];

  unsigned int* bfrag = (unsigned int*)((char*)d_ws + OFF_BF_BYTES);
  float*        sT    = (float*)((char*)d_ws + OFF_ST_BYTES);
  float*        out   = (float*)d_out;

  precompute_bfrag<<<dim3(KSTEPS, C_CH / 8), dim3(256), 0, stream>>>(
      U3, U2, U1, w3, w2, w1, bfrag);
  contract_mfma<<<dim3(C_CH / 4, B_NODES / NODES_PER_BLK), dim3(256), 0, stream>>>(
      x, (const short8*)bfrag, sT);
  linear_kernel<<<dim3(B_NODES / 64, C_CH / 64), dim3(256), 0, stream>>>(sT, Wl, out);
}